// Round 7
// baseline (131.275 us; speedup 1.0000x reference)
//
#include <hip/hip_runtime.h>

#define IN_C 64
#define OUT_C 16
#define EA_D 8

typedef float v2f __attribute__((ext_vector_type(2)));
typedef float v4f __attribute__((ext_vector_type(4)));

__device__ __forceinline__ void atomic_add_f32(float* p, float v) {
#if defined(__HIP_PLATFORM_AMD__) || defined(__AMDGCN__)
    unsafeAtomicAdd(p, v);   // global_atomic_add_f32, no CAS loop
#else
    atomicAdd(p, v);
#endif
}

// ---------------- h = x @ lin_w + lin_b  (also zeroes out[]) ----------------
// block = 256 threads = 16 nodes x 16 channels; LDS reads are b128; the
// 64-FMA dot runs as 32 v_pk_fma_f32 via a float4 accumulator.
__global__ __launch_bounds__(256) void h_kernel(
    const float* __restrict__ x,
    const float* __restrict__ lin_w,   // [64,16]
    const float* __restrict__ lin_b,   // [16]
    float* __restrict__ h,             // [N,16]
    float* __restrict__ out,           // [N,16] zero-init
    int n)
{
    __shared__ float s_x [16][IN_C + 4];   // stride 68: 16B-aligned, 2-way banks (free)
    __shared__ float s_wt[16][IN_C + 4];   // transposed W: s_wt[c][k]

    const int t = threadIdx.x;
    const int nodeBase = blockIdx.x * 16;

    // zero out[] early: store latency hides under the FMA loop below
    {
        const int idx = nodeBase * OUT_C + t;      // 256 consecutive elements
        if (idx < n * OUT_C) out[idx] = 0.0f;
    }

    for (int i = t; i < IN_C * OUT_C; i += 256)
        s_wt[i & 15][i >> 4] = lin_w[i];

    {
        const int lr = t >> 4;            // row 0..15
        const int k4 = (t & 15) * 4;      // col 0,4,...,60
        const int node = nodeBase + lr;
        float4 v = make_float4(0.f, 0.f, 0.f, 0.f);
        if (node < n) v = *(const float4*)(x + (size_t)node * IN_C + k4);
        *(float4*)(&s_x[lr][k4]) = v;
    }
    __syncthreads();

    const int lr = t >> 4;
    const int c  = t & 15;
    const int node = nodeBase + lr;
    if (node < n) {
        v4f acc4 = {0.f, 0.f, 0.f, 0.f};
        #pragma unroll
        for (int k4 = 0; k4 < IN_C; k4 += 4) {
            const v4f xv = *(const v4f*)(&s_x [lr][k4]);  // quad broadcast
            const v4f wv = *(const v4f*)(&s_wt[c ][k4]);  // 2-way banks (free)
            acc4 = acc4 + xv * wv;                         // v_pk_fma_f32 x2
        }
        h[(size_t)node * OUT_C + c] =
            lin_b[c] + ((acc4.x + acc4.y) + (acc4.z + acc4.w));
    }
}

// ---------------- per-edge fused kernel: quad-per-edge ----------------
// lane = (edge, channel). ea_w stored transposed [c][k] stride 12 -> the
// 8-term dot is 2 ds_read_b128 + packed FMAs. MLP runs as float2 packed
// (v_pk_fma/v_pk_max). Softmax via shfl_xor within the 16-lane quad.
// Scatter naturally grouped: 16 lanes = one 64B out line.
__global__ __launch_bounds__(256) void edge_kernel(
    const int*   __restrict__ edge_index,  // [2,E]
    const float* __restrict__ edge_attr,   // [E,8]
    const float* __restrict__ ea_w,        // [8,16]
    const float* __restrict__ ea_b,        // [16]
    const float* __restrict__ w1,          // [16]
    const float* __restrict__ b1,          // [16]
    const float* __restrict__ w2,          // [16]
    const float* __restrict__ b2,          // [1]
    const float* __restrict__ h,           // [N,16]
    float*       __restrict__ out,         // [N,16]
    int E)
{
    __shared__ float s_eawT[OUT_C][12];    // [c][k], stride 12: 2-way banks (free)
    __shared__ float s_eab[OUT_C];

    const int t = threadIdx.x;
    if (t < 128) {
        const int kk = t >> 4, cc = t & 15;
        s_eawT[cc][kk] = ea_w[t];          // ea_w[kk*16+cc] == ea_w[t]
    } else if (t < 128 + OUT_C) {
        s_eab[t - 128] = ea_b[t - 128];
    }
    __syncthreads();

    const int gid = blockIdx.x * 256 + t;
    const int e = gid >> 4;
    const int c = gid & 15;
    if (e >= E) return;

    const int row = edge_index[e] - 1;     // edge_index[0][e] - 1
    const int col = edge_index[E + e];     // edge_index[1][e]

    // 32B broadcast per quad (contiguous across the 4 quads of a wave)
    const float4* ap = (const float4*)(edge_attr + (size_t)e * EA_D);
    const float4 a0 = ap[0], a1 = ap[1];

    // gather: 16 consecutive lanes read one 64B line of h
    const float hv = h[(size_t)col * OUT_C + c];

    // agg = h[col][c] * (edge_attr @ ea_w + ea_b)[c]  -- packed dot
    const v4f e0 = *(const v4f*)(&s_eawT[c][0]);
    const v4f e1 = *(const v4f*)(&s_eawT[c][4]);
    const v4f av0 = {a0.x, a0.y, a0.z, a0.w};
    const v4f av1 = {a1.x, a1.y, a1.z, a1.w};
    const v4f d4 = av0 * e0 + av1 * e1;
    const float d = s_eab[c] + ((d4.x + d4.y) + (d4.z + d4.w));
    const float agg = hv * d;

    // score = b2 + sum_j relu(agg*w1[j]+b1[j])*w2[j]  -- packed MLP
    // w1/b1/w2 at uniform addresses -> scalar (SGPR) loads
    const v2f* w1v = (const v2f*)w1;
    const v2f* b1v = (const v2f*)b1;
    const v2f* w2v = (const v2f*)w2;
    const v2f agg2 = {agg, agg};
    v2f acc2 = {0.f, 0.f};
    #pragma unroll
    for (int j = 0; j < OUT_C / 2; ++j) {
        v2f hm = agg2 * w1v[j] + b1v[j];                      // v_pk_fma_f32
        hm = __builtin_elementwise_max(hm, (v2f){0.f, 0.f});  // v_pk_max_f32
        acc2 = acc2 + hm * w2v[j];                            // v_pk_fma_f32
    }
    const float s = b2[0] + acc2.x + acc2.y;

    // softmax over the 16 channels of this quad
    float mx = s;
    mx = fmaxf(mx, __shfl_xor(mx, 1));
    mx = fmaxf(mx, __shfl_xor(mx, 2));
    mx = fmaxf(mx, __shfl_xor(mx, 4));
    mx = fmaxf(mx, __shfl_xor(mx, 8));
    const float p = __expf(s - mx);
    float den = p;
    den += __shfl_xor(den, 1);
    den += __shfl_xor(den, 2);
    den += __shfl_xor(den, 4);
    den += __shfl_xor(den, 8);

    // grouped scatter: one 64B line per quad
    atomic_add_f32(out + (size_t)row * OUT_C + c,
                   agg * p * __builtin_amdgcn_rcpf(den));
}

extern "C" void kernel_launch(void* const* d_in, const int* in_sizes, int n_in,
                              void* d_out, int out_size, void* d_ws, size_t ws_size,
                              hipStream_t stream)
{
    const float* x          = (const float*)d_in[0];
    const int*   edge_index = (const int*)  d_in[1];
    const float* edge_attr  = (const float*)d_in[2];
    const float* lin_w      = (const float*)d_in[3];
    const float* lin_b      = (const float*)d_in[4];
    const float* ea_w       = (const float*)d_in[5];
    const float* ea_b       = (const float*)d_in[6];
    const float* attn_w1    = (const float*)d_in[7];
    const float* attn_b1    = (const float*)d_in[8];
    const float* attn_w2    = (const float*)d_in[9];
    const float* attn_b2    = (const float*)d_in[10];

    const int n = in_sizes[0] / IN_C;      // 100000
    const int E = in_sizes[1] / 2;         // 400000

    float* h   = (float*)d_ws;             // [N,16] = 6.4 MB
    float* out = (float*)d_out;

    // h_kernel zeroes out[] (grid covers every out element exactly once)
    h_kernel<<<(n + 15) / 16, 256, 0, stream>>>(x, lin_w, lin_b, h, out, n);

    // 16 lanes per edge
    const long long threads = (long long)E * OUT_C;
    edge_kernel<<<(int)((threads + 255) / 256), 256, 0, stream>>>(
        edge_index, edge_attr, ea_w, ea_b,
        attn_w1, attn_b1, attn_w2, attn_b2,
        h, out, E);
}